// Round 21
// baseline (76.280 us; speedup 1.0000x reference)
//
#include <hip/hip_runtime.h>
#include <math.h>

#define N 4096
#define D 512
#define KPOS 5
#define KNEG 10
#define NB 32                      // 4096/128 block-rows
#define NPAIR (NB * (NB - 1) / 2)  // 496 strict upper pairs
#define NJOB 1024                  // 992 off-diag half-jobs + 32 diag half-jobs

typedef short s16x8 __attribute__((ext_vector_type(8)));
typedef unsigned short u16x8 __attribute__((ext_vector_type(8)));
typedef unsigned short u16x4 __attribute__((ext_vector_type(4)));
typedef unsigned u32x4 __attribute__((ext_vector_type(4)));
typedef float f32x4 __attribute__((ext_vector_type(4)));

__device__ __forceinline__ unsigned short f2bf(float x) {
    unsigned u = __float_as_uint(x);
    unsigned r = (u + 0x7FFFu + ((u >> 16) & 1u)) >> 16;   // RNE
    return (unsigned short)r;
}
// bf16 -> sortable u16 (ascending u16 order == ascending float order)
__device__ __forceinline__ unsigned short mapbf(float x) {
    const unsigned short h = f2bf(x);
    return h ^ ((h & 0x8000u) ? 0xFFFFu : 0x8000u);
}
__device__ __forceinline__ unsigned umax_(unsigned a, unsigned b) { return a > b ? a : b; }
__device__ __forceinline__ unsigned umin_(unsigned a, unsigned b) { return a < b ? a : b; }
__device__ __forceinline__ unsigned pkmax(unsigned a, unsigned b) {
    unsigned r; asm("v_pk_max_u16 %0, %1, %2" : "=v"(r) : "v"(a), "v"(b)); return r;
}
__device__ __forceinline__ unsigned pkmin(unsigned a, unsigned b) {
    unsigned r; asm("v_pk_min_u16 %0, %1, %2" : "=v"(r) : "v"(a), "v"(b)); return r;
}

// ---- DPP cross-lane (VALU latency, replaces DS-path __shfl_xor) ----------
#define DPPU(old, v, ctrl, rm) \
    ((unsigned)__builtin_amdgcn_update_dpp((int)(old), (int)(v), (ctrl), (rm), 0xF, false))

__device__ __forceinline__ unsigned wave_max_b(unsigned v) {   // -> SGPR bcast
    v = umax_(v, DPPU(0u, v, 0x121, 0xF));
    v = umax_(v, DPPU(0u, v, 0x122, 0xF));
    v = umax_(v, DPPU(0u, v, 0x124, 0xF));
    v = umax_(v, DPPU(0u, v, 0x128, 0xF));
    v = umax_(v, DPPU(0u, v, 0x142, 0xA));
    v = umax_(v, DPPU(0u, v, 0x143, 0xC));
    return (unsigned)__builtin_amdgcn_readlane((int)v, 63);
}
__device__ __forceinline__ unsigned wave_min_b(unsigned v) {
    v = umin_(v, DPPU(0xFFFFFFFFu, v, 0x121, 0xF));
    v = umin_(v, DPPU(0xFFFFFFFFu, v, 0x122, 0xF));
    v = umin_(v, DPPU(0xFFFFFFFFu, v, 0x124, 0xF));
    v = umin_(v, DPPU(0xFFFFFFFFu, v, 0x128, 0xF));
    v = umin_(v, DPPU(0xFFFFFFFFu, v, 0x142, 0xA));
    v = umin_(v, DPPU(0xFFFFFFFFu, v, 0x143, 0xC));
    return (unsigned)__builtin_amdgcn_readlane((int)v, 63);
}
__device__ __forceinline__ float row_allmax_f(float v) {       // 16-lane all-reduce
    v = fmaxf(v, __uint_as_float(DPPU(0xFF800000u, __float_as_uint(v), 0x121, 0xF)));
    v = fmaxf(v, __uint_as_float(DPPU(0xFF800000u, __float_as_uint(v), 0x122, 0xF)));
    v = fmaxf(v, __uint_as_float(DPPU(0xFF800000u, __float_as_uint(v), 0x124, 0xF)));
    v = fmaxf(v, __uint_as_float(DPPU(0xFF800000u, __float_as_uint(v), 0x128, 0xF)));
    return v;
}
__device__ __forceinline__ float row_allsum_f(float v) {
    v += __uint_as_float(DPPU(0u, __float_as_uint(v), 0x121, 0xF));
    v += __uint_as_float(DPPU(0u, __float_as_uint(v), 0x122, 0xF));
    v += __uint_as_float(DPPU(0u, __float_as_uint(v), 0x124, 0xF));
    v += __uint_as_float(DPPU(0u, __float_as_uint(v), 0x128, 0xF));
    return v;
}
__device__ __forceinline__ float wave_sum_f(float v) {         // -> SGPR bcast
    v = row_allsum_f(v);
    v += __uint_as_float(DPPU(0u, __float_as_uint(v), 0x142, 0xA));
    v += __uint_as_float(DPPU(0u, __float_as_uint(v), 0x143, 0xC));
    return __uint_as_float((unsigned)__builtin_amdgcn_readlane((int)__float_as_uint(v), 63));
}

// ---------------------------------------------------------------------------
// Kernel 1: normalize. anchor rows (eps 1e-8) -> bf16 A; sample rows
// (eps 1e-12) -> bf16 s_norm. float4 input loads (2/lane).
// ---------------------------------------------------------------------------
__global__ __launch_bounds__(256) void norm_kernel(const float* __restrict__ anchor,
                                                   const float* __restrict__ sample,
                                                   unsigned short* __restrict__ Abf,
                                                   unsigned short* __restrict__ s_norm) {
    const int wave = threadIdx.x >> 6, lane = threadIdx.x & 63;
    const int row = blockIdx.x * 4 + wave;
    const bool is_anchor = row < N;
    const float* in = is_anchor ? anchor + (size_t)row * D
                                : sample + (size_t)(row - N) * D;
    const float eps = is_anchor ? 1e-8f : 1e-12f;

    const float4 v0 = *(const float4*)&in[lane * 4];
    const float4 v1 = *(const float4*)&in[256 + lane * 4];
    float ss = v0.x * v0.x + v0.y * v0.y + v0.z * v0.z + v0.w * v0.w
             + v1.x * v1.x + v1.y * v1.y + v1.z * v1.z + v1.w * v1.w;
#pragma unroll
    for (int off = 32; off > 0; off >>= 1) ss += __shfl_xor(ss, off);
    const float inv = 1.0f / fmaxf(sqrtf(ss), eps);

    unsigned short* out = is_anchor ? Abf + (size_t)row * D
                                    : s_norm + (size_t)(row - N) * D;
    ushort4 o0, o1;
    o0.x = f2bf(v0.x * inv); o0.y = f2bf(v0.y * inv);
    o0.z = f2bf(v0.z * inv); o0.w = f2bf(v0.w * inv);
    o1.x = f2bf(v1.x * inv); o1.y = f2bf(v1.y * inv);
    o1.z = f2bf(v1.z * inv); o1.w = f2bf(v1.w * inv);
    *(ushort4*)&out[lane * 4] = o0;
    *(ushort4*)&out[256 + lane * 4] = o1;
}

// ---------------------------------------------------------------------------
// Kernel 2: sim = A@A^T, bf16 MFMA, K = 512. 1024 balanced half-jobs
// (128 rows x 64 cols). Output = SORTABLE-MAPPED u16, written with
// NONTEMPORAL stores (stream past the per-XCD L2 -> reader gets clean
// L3/HBM lines instead of pulling dirty lines from remote L2s).
// ---------------------------------------------------------------------------
#define ATILE (128 * 64)
#define BTILE (64 * 64)

__device__ __forceinline__ void stage_ab(const unsigned short* __restrict__ A,
                                         unsigned short* As, unsigned short* Bs,
                                         int rowA, int colB, int kl, int t) {
#pragma unroll
    for (int i = 0; i < 4; ++i) {
        const int c = i * 256 + t;                 // 16B chunk id 0..1023
        const int r = c >> 3;                      // tile row 0..127
        const int ke = ((c & 7) ^ (r & 7)) * 8;    // swizzled k-element offset
        __builtin_amdgcn_global_load_lds(
            (const __attribute__((address_space(1))) void*)(A + (size_t)(rowA + r) * D + kl + ke),
            (__attribute__((address_space(3))) void*)(As + c * 8), 16, 0, 0);
    }
#pragma unroll
    for (int i = 0; i < 2; ++i) {
        const int c = i * 256 + t;                 // 0..511
        const int r = c >> 3;                      // B tile row 0..63
        const int ke = ((c & 7) ^ (r & 7)) * 8;
        __builtin_amdgcn_global_load_lds(
            (const __attribute__((address_space(1))) void*)(A + (size_t)(colB + r) * D + kl + ke),
            (__attribute__((address_space(3))) void*)(Bs + c * 8), 16, 0, 0);
    }
}

__global__ __launch_bounds__(256) void gemm_bf16(const unsigned short* __restrict__ Abf,
                                                 unsigned short* __restrict__ C) {
    // T1: XCD chunk swizzle (bijective, NJOB % 8 == 0).
    const int q = (blockIdx.x % 8) * (NJOB / 8) + blockIdx.x / 8;

    int bi, bj, h;
    if (q < 2 * NPAIR) {
        const int op = q >> 1;                 // strict pair index 0..495
        h = q & 1;
        bi = (int)(31.5f - sqrtf(31.5f * 31.5f - 2.f * (float)op));
        while (31 * bi - bi * (bi - 1) / 2 > op) --bi;
        while (31 * (bi + 1) - (bi + 1) * bi / 2 <= op) ++bi;
        bj = bi + 1 + (op - (31 * bi - bi * (bi - 1) / 2));
    } else {
        const int d = q - 2 * NPAIR;           // 0..31
        bi = bj = d >> 1;
        h = d & 1;
    }

    __shared__ __align__(16) unsigned short As[2 * ATILE];   // 2 x 16 KiB
    __shared__ __align__(16) unsigned short Bs[2 * BTILE];   // 2 x 8 KiB

    const int t = threadIdx.x;
    const int l = t & 63;
    const int w = t >> 6;
    const int wr = w >> 1, wc = w & 1;         // wave tile: 64 rows x 32 cols
    const int rowA = bi * 128;
    const int colB = bj * 128 + h * 64;
    const int lrow = l & 15, lgrp = l >> 4;

    f32x4 acc[4][2];
#pragma unroll
    for (int m = 0; m < 4; ++m)
#pragma unroll
        for (int n = 0; n < 2; ++n) acc[m][n] = (f32x4){0.f, 0.f, 0.f, 0.f};

    stage_ab(Abf, As, Bs, rowA, colB, 0, t);
    __syncthreads();

    for (int kc = 0; kc < 8; ++kc) {
        const int cur = kc & 1;
        if (kc < 7)
            stage_ab(Abf, As + (cur ^ 1) * ATILE, Bs + (cur ^ 1) * BTILE,
                     rowA, colB, (kc + 1) * 64, t);

        const char* AsB = (const char*)(As + cur * ATILE);
        const char* BsB = (const char*)(Bs + cur * BTILE);
#pragma unroll
        for (int kk = 0; kk < 2; ++kk) {
            s16x8 af[4], bfr[2];
#pragma unroll
            for (int m = 0; m < 4; ++m) {
                const int row = wr * 64 + m * 16 + lrow;
                af[m] = *(const s16x8*)(AsB + row * 128 + (((kk * 4 + lgrp) ^ (row & 7)) * 16));
            }
#pragma unroll
            for (int n = 0; n < 2; ++n) {
                const int row = wc * 32 + n * 16 + lrow;   // B tile row 0..63
                bfr[n] = *(const s16x8*)(BsB + row * 128 + (((kk * 4 + lgrp) ^ (row & 7)) * 16));
            }
#pragma unroll
            for (int m = 0; m < 4; ++m)
#pragma unroll
                for (int n = 0; n < 2; ++n)
                    acc[m][n] = __builtin_amdgcn_mfma_f32_16x16x32_bf16(af[m], bfr[n], acc[m][n], 0, 0, 0);
        }
        __syncthreads();
    }

    // C/D layout: col = lane&15, row = (lane>>4)*4 + j ; NONTEMPORAL stores.
#pragma unroll
    for (int m = 0; m < 4; ++m) {
#pragma unroll
        for (int n = 0; n < 2; ++n) {
            const int col = colB + wc * 32 + n * 16 + lrow;
            const int row0 = rowA + wr * 64 + m * 16 + lgrp * 4;
#pragma unroll
            for (int j = 0; j < 4; ++j)
                __builtin_nontemporal_store(mapbf(acc[m][n][j]),
                                            &C[(size_t)(row0 + j) * N + col]);
        }
    }
    if (bi != bj) {
#pragma unroll
        for (int m = 0; m < 4; ++m) {
#pragma unroll
            for (int n = 0; n < 2; ++n) {
                const int col = colB + wc * 32 + n * 16 + lrow;
                const int row0 = rowA + wr * 64 + m * 16 + lgrp * 4;
                u16x4 pk;
                pk.x = mapbf(acc[m][n][0]);
                pk.y = mapbf(acc[m][n][1]);
                pk.z = mapbf(acc[m][n][2]);
                pk.w = mapbf(acc[m][n][3]);
                __builtin_nontemporal_store(pk, (u16x4*)&C[(size_t)col * N + row0]);
            }
        }
    }
}

// ---------------------------------------------------------------------------
// Kernel 3: FUSED topk + loss. Threshold two-pass scan (ballot binary-search
// thresholds, DPP merges/softmax); sim rows read with NONTEMPORAL loads
// (read-once streaming data, keeps L2 clean for s_norm).
// ---------------------------------------------------------------------------
__device__ __forceinline__ void ins_top(unsigned* tk, unsigned c) {
#pragma unroll
    for (int q = 0; q < KPOS - 1; ++q) {
        const unsigned x = umax_(tk[q], c);
        c = umin_(tk[q], c);
        tk[q] = x;
    }
    tk[KPOS - 1] = umax_(tk[KPOS - 1], c);
}
__device__ __forceinline__ void ins_bot(unsigned* bk, unsigned c) {
#pragma unroll
    for (int q = 0; q < KNEG - 1; ++q) {
        const unsigned x = umin_(bk[q], c);
        c = umax_(bk[q], c);
        bk[q] = x;
    }
    bk[KNEG - 1] = umin_(bk[KNEG - 1], c);
}

__global__ __launch_bounds__(256) void fused_topk_loss(const unsigned short* __restrict__ sim,
                                                       const unsigned short* __restrict__ s_norm,
                                                       float* __restrict__ partials) {
    __shared__ float wsum[4];
    __shared__ unsigned cand_top[4][256];
    __shared__ unsigned cand_bot[4][256];
    __shared__ unsigned cnt[4][2];
    const int wave = threadIdx.x >> 6, lane = threadIdx.x & 63;
    const int ia = blockIdx.x * 4 + wave;
    const unsigned short* s = sim + (size_t)ia * N;
    const int cc = lane & 15;               // loss column selector
    const int g = lane >> 4;                // loss k-group

    if (lane == 0) { cnt[wave][0] = 0u; cnt[wave][1] = 0u; }

    // ---- preload the whole row: 8 independent NT 16B loads in flight ----
    const u32x4 d0 = __builtin_bit_cast(u32x4, __builtin_nontemporal_load((const u16x8*)&s[8 * lane]));
    const u32x4 d1 = __builtin_bit_cast(u32x4, __builtin_nontemporal_load((const u16x8*)&s[8 * (lane + 64)]));
    const u32x4 d2 = __builtin_bit_cast(u32x4, __builtin_nontemporal_load((const u16x8*)&s[8 * (lane + 128)]));
    const u32x4 d3 = __builtin_bit_cast(u32x4, __builtin_nontemporal_load((const u16x8*)&s[8 * (lane + 192)]));
    const u32x4 d4 = __builtin_bit_cast(u32x4, __builtin_nontemporal_load((const u16x8*)&s[8 * (lane + 256)]));
    const u32x4 d5 = __builtin_bit_cast(u32x4, __builtin_nontemporal_load((const u16x8*)&s[8 * (lane + 320)]));
    const u32x4 d6 = __builtin_bit_cast(u32x4, __builtin_nontemporal_load((const u16x8*)&s[8 * (lane + 384)]));
    const u32x4 d7 = __builtin_bit_cast(u32x4, __builtin_nontemporal_load((const u16x8*)&s[8 * (lane + 448)]));
    __builtin_amdgcn_sched_barrier(0);
    asm volatile("" ::: "memory");

    // ---- pass 1: lane max/min via packed trees ----
#define VMAX(v) pkmax(pkmax(v.x, v.y), pkmax(v.z, v.w))
#define VMIN(v) pkmin(pkmin(v.x, v.y), pkmin(v.z, v.w))
    unsigned mx = VMAX(d0), mn = VMIN(d0);
    mx = pkmax(mx, VMAX(d1)); mn = pkmin(mn, VMIN(d1));
    mx = pkmax(mx, VMAX(d2)); mn = pkmin(mn, VMIN(d2));
    mx = pkmax(mx, VMAX(d3)); mn = pkmin(mn, VMIN(d3));
    mx = pkmax(mx, VMAX(d4)); mn = pkmin(mn, VMIN(d4));
    mx = pkmax(mx, VMAX(d5)); mn = pkmin(mn, VMIN(d5));
    mx = pkmax(mx, VMAX(d6)); mn = pkmin(mn, VMIN(d6));
    mx = pkmax(mx, VMAX(d7)); mn = pkmin(mn, VMIN(d7));
#undef VMAX
#undef VMIN
    const unsigned lm = umax_(mx >> 16, mx & 0xFFFFu);
    const unsigned ln = umin_(mn >> 16, mn & 0xFFFFu);

    // ---- thresholds via ballot binary search (no DS-path ops) ----
    unsigned lo = 0u, hi = 0xFFFFu;
    while (lo < hi) {
        const unsigned mid = (lo + hi + 1u) >> 1;
        const int c = __popcll(__ballot(lm >= mid));
        if (c >= KPOS) lo = mid; else hi = mid - 1u;
    }
    const unsigned T5 = lo;
    lo = 0u; hi = 0xFFFFu;
    while (lo < hi) {
        const unsigned mid = (lo + hi) >> 1;
        const int c = __popcll(__ballot(ln <= mid));
        if (c >= KNEG) hi = mid; else lo = mid + 1u;
    }
    const unsigned T10 = lo;

    const unsigned t5g = (T5 == 0u) ? 0u : T5 - 1u;
    const unsigned t10g = (T10 >= 0xFFFFu) ? 0xFFFFu : T10 + 1u;
    const unsigned pair5 = t5g * 0x10001u;
    const unsigned pairA = t10g * 0x10001u;

    // ---- pass 2: sparse exact candidate collection ----
#define SCAN_DW(dd, base)                                                      \
    {                                                                          \
        const unsigned pt = pkmax(dd, pair5);                                  \
        const unsigned pb = pkmin(dd, pairA);                                  \
        if (pt != pair5 || pb != pairA) {                                      \
            const unsigned e0 = (dd) & 0xFFFFu, e1 = (dd) >> 16;               \
            if (e0 >= T5) { unsigned p = atomicAdd(&cnt[wave][0], 1u);         \
                cand_top[wave][p & 255u] = (e0 << 16) | (unsigned)((base) ^ 0xFFF); } \
            if (e1 >= T5) { unsigned p = atomicAdd(&cnt[wave][0], 1u);         \
                cand_top[wave][p & 255u] = (e1 << 16) | (unsigned)(((base) + 1) ^ 0xFFF); } \
            if (e0 <= T10) { unsigned p = atomicAdd(&cnt[wave][1], 1u);        \
                cand_bot[wave][p & 255u] = (e0 << 16) | (unsigned)(base); }    \
            if (e1 <= T10) { unsigned p = atomicAdd(&cnt[wave][1], 1u);        \
                cand_bot[wave][p & 255u] = (e1 << 16) | (unsigned)((base) + 1); } \
        }                                                                      \
    }
#define SCAN_VEC(dv, vb)                                                       \
    SCAN_DW(dv.x, (vb));      SCAN_DW(dv.y, (vb) + 2);                         \
    SCAN_DW(dv.z, (vb) + 4);  SCAN_DW(dv.w, (vb) + 6);
    SCAN_VEC(d0, 8 * lane)
    SCAN_VEC(d1, 8 * (lane + 64))
    SCAN_VEC(d2, 8 * (lane + 128))
    SCAN_VEC(d3, 8 * (lane + 192))
    SCAN_VEC(d4, 8 * (lane + 256))
    SCAN_VEC(d5, 8 * (lane + 320))
    SCAN_VEC(d6, 8 * (lane + 384))
    SCAN_VEC(d7, 8 * (lane + 448))
#undef SCAN_VEC
#undef SCAN_DW

    // ---- final exact selection from candidates (DPP wave merges) ----
    const unsigned ctT = umin_(cnt[wave][0], 256u);
    const unsigned ctB = umin_(cnt[wave][1], 256u);
    unsigned tk[KPOS], bk[KNEG];
#pragma unroll
    for (int q = 0; q < KPOS; ++q) tk[q] = 0u;
#pragma unroll
    for (int q = 0; q < KNEG; ++q) bk[q] = 0xFFFFFFFFu;
    for (unsigned c = lane; c < ctT; c += 64) ins_top(tk, cand_top[wave][c]);
    for (unsigned c = lane; c < ctB; c += 64) ins_bot(bk, cand_bot[wave][c]);

    int rowB = 0;                            // (cc==15 dummy stays 0)
#pragma unroll
    for (int it = 0; it < KPOS; ++it) {
        const unsigned m = wave_max_b(tk[0]);
        if (cc == it) rowB = (int)((m & 0xFFFu) ^ 0xFFFu);
        if (tk[0] == m) {
#pragma unroll
            for (int q = 0; q < KPOS - 1; ++q) tk[q] = tk[q + 1];
            tk[KPOS - 1] = 0u;
        }
    }
#pragma unroll
    for (int it = 0; it < KNEG; ++it) {
        const unsigned m = wave_min_b(bk[0]);
        if (cc == KPOS + it) rowB = (int)(m & 0xFFFu);
        if (bk[0] == m) {
#pragma unroll
            for (int q = 0; q < KNEG - 1; ++q) bk[q] = bk[q + 1];
            bk[KNEG - 1] = 0xFFFFFFFFu;
        }
    }

    // ---- loss: A rows = query rows (ia*5+p mod N), B cols = pos/neg ----
    const int rowA = (ia * KPOS + ((cc < KPOS) ? cc : 0)) & (N - 1);
    const unsigned short* pA = s_norm + (size_t)rowA * D + g * 8;
    const unsigned short* pB = s_norm + (size_t)rowB * D + g * 8;

    s16x8 a[16], b[16];
#pragma unroll
    for (int kk = 0; kk < 16; ++kk) {
        a[kk] = *(const s16x8*)(pA + kk * 32);
        b[kk] = *(const s16x8*)(pB + kk * 32);
    }
    __builtin_amdgcn_sched_barrier(0);      // pin: all 32 loads issued first
    asm volatile("" ::: "memory");

    f32x4 acc = (f32x4){0.f, 0.f, 0.f, 0.f};
#pragma unroll
    for (int kk = 0; kk < 16; ++kk)
        acc = __builtin_amdgcn_mfma_f32_16x16x32_bf16(a[kk], b[kk], acc, 0, 0, 0);

    float lsum = 0.f;
#pragma unroll
    for (int j = 0; j < 4; ++j) {
        const int p = g * 4 + j;                 // output row (query p)
        const float logit = acc[j] * 10.f;
        const bool isneg = (cc >= KPOS) && (cc < 15);
        const bool ispos = (cc == p);
        const float x = (ispos || isneg) ? logit : -__builtin_inff();
        const float m = row_allmax_f(x);                     // DPP 16-lane
        const float e = (ispos || isneg) ? expf(logit - m) : 0.f;
        const float sx = row_allsum_f(e);                    // DPP 16-lane
        const float l0 = row_allsum_f(ispos ? logit : 0.f);  // DPP 16-lane
        if (p < KPOS && ispos) lsum += logf(sx) + m - l0;    // one lane per row
    }

    const float ltot = wave_sum_f(lsum);
    if (lane == 0) wsum[wave] = ltot;
    __syncthreads();
    if (threadIdx.x == 0)
        partials[blockIdx.x] = wsum[0] + wsum[1] + wsum[2] + wsum[3];
}

// ---------------------------------------------------------------------------
// Kernel 4: final deterministic reduce of 1024 block partials.
// ---------------------------------------------------------------------------
__global__ __launch_bounds__(256) void reduce_kernel(const float* __restrict__ partials,
                                                     float* __restrict__ out) {
    __shared__ float wsum[4];
    const int wave = threadIdx.x >> 6, lane = threadIdx.x & 63;
    float s = partials[threadIdx.x] + partials[threadIdx.x + 256] +
              partials[threadIdx.x + 512] + partials[threadIdx.x + 768];
#pragma unroll
    for (int off = 32; off > 0; off >>= 1) s += __shfl_xor(s, off);
    if (lane == 0) wsum[wave] = s;
    __syncthreads();
    if (threadIdx.x == 0)
        *out = (wsum[0] + wsum[1] + wsum[2] + wsum[3]) * (1.0f / (float)(N * KPOS));
}

// ---------------------------------------------------------------------------
extern "C" void kernel_launch(void* const* d_in, const int* in_sizes, int n_in,
                              void* d_out, int out_size, void* d_ws, size_t ws_size,
                              hipStream_t stream) {
    const float* anchor = (const float*)d_in[0];
    const float* sample = (const float*)d_in[1];
    float* out = (float*)d_out;

    char* ws = (char*)d_ws;
    unsigned short* Abf    = (unsigned short*)ws;                               // 4 MiB
    unsigned short* s_norm = (unsigned short*)(ws + (size_t)4 * 1024 * 1024);   // 4 MiB
    unsigned short* sim    = (unsigned short*)(ws + (size_t)8 * 1024 * 1024);   // 32 MiB
    float* partials = (float*)(ws + (size_t)40 * 1024 * 1024);                  // 4 KiB
    unsigned* counter = (unsigned*)(ws + (size_t)40 * 1024 * 1024 + 4096);
    (void)counter;

    norm_kernel<<<2048, 256, 0, stream>>>(anchor, sample, Abf, s_norm);

    gemm_bf16<<<NJOB, 256, 0, stream>>>(Abf, sim);

    fused_topk_loss<<<N / 4, 256, 0, stream>>>(sim, s_norm, partials);

    reduce_kernel<<<1, 256, 0, stream>>>(partials, out);
}

// Round 22
// 59.989 us; speedup vs baseline: 1.2716x; 1.2716x over previous
//
#include <hip/hip_runtime.h>
#include <math.h>

#define N 4096
#define D 512
#define KPOS 5
#define KNEG 10
#define NB 32                      // 4096/128 block-rows
#define NPAIR (NB * (NB - 1) / 2)  // 496 strict upper pairs
#define NJOB 1024                  // 992 off-diag half-jobs + 32 diag half-jobs

typedef short s16x8 __attribute__((ext_vector_type(8)));
typedef unsigned short u16x8 __attribute__((ext_vector_type(8)));
typedef unsigned u32x4 __attribute__((ext_vector_type(4)));
typedef float f32x4 __attribute__((ext_vector_type(4)));

__device__ __forceinline__ unsigned short f2bf(float x) {
    unsigned u = __float_as_uint(x);
    unsigned r = (u + 0x7FFFu + ((u >> 16) & 1u)) >> 16;   // RNE
    return (unsigned short)r;
}
// bf16 -> sortable u16 (ascending u16 order == ascending float order)
__device__ __forceinline__ unsigned short mapbf(float x) {
    const unsigned short h = f2bf(x);
    return h ^ ((h & 0x8000u) ? 0xFFFFu : 0x8000u);
}
__device__ __forceinline__ unsigned umax_(unsigned a, unsigned b) { return a > b ? a : b; }
__device__ __forceinline__ unsigned umin_(unsigned a, unsigned b) { return a < b ? a : b; }
__device__ __forceinline__ unsigned pkmax(unsigned a, unsigned b) {
    unsigned r; asm("v_pk_max_u16 %0, %1, %2" : "=v"(r) : "v"(a), "v"(b)); return r;
}
__device__ __forceinline__ unsigned pkmin(unsigned a, unsigned b) {
    unsigned r; asm("v_pk_min_u16 %0, %1, %2" : "=v"(r) : "v"(a), "v"(b)); return r;
}

// ---- DPP cross-lane (VALU latency, replaces DS-path __shfl_xor) ----------
#define DPPU(old, v, ctrl, rm) \
    ((unsigned)__builtin_amdgcn_update_dpp((int)(old), (int)(v), (ctrl), (rm), 0xF, false))

__device__ __forceinline__ unsigned wave_max_b(unsigned v) {   // -> SGPR bcast
    v = umax_(v, DPPU(0u, v, 0x121, 0xF));
    v = umax_(v, DPPU(0u, v, 0x122, 0xF));
    v = umax_(v, DPPU(0u, v, 0x124, 0xF));
    v = umax_(v, DPPU(0u, v, 0x128, 0xF));
    v = umax_(v, DPPU(0u, v, 0x142, 0xA));
    v = umax_(v, DPPU(0u, v, 0x143, 0xC));
    return (unsigned)__builtin_amdgcn_readlane((int)v, 63);
}
__device__ __forceinline__ unsigned wave_min_b(unsigned v) {
    v = umin_(v, DPPU(0xFFFFFFFFu, v, 0x121, 0xF));
    v = umin_(v, DPPU(0xFFFFFFFFu, v, 0x122, 0xF));
    v = umin_(v, DPPU(0xFFFFFFFFu, v, 0x124, 0xF));
    v = umin_(v, DPPU(0xFFFFFFFFu, v, 0x128, 0xF));
    v = umin_(v, DPPU(0xFFFFFFFFu, v, 0x142, 0xA));
    v = umin_(v, DPPU(0xFFFFFFFFu, v, 0x143, 0xC));
    return (unsigned)__builtin_amdgcn_readlane((int)v, 63);
}
__device__ __forceinline__ float row_allmax_f(float v) {       // 16-lane all-reduce
    v = fmaxf(v, __uint_as_float(DPPU(0xFF800000u, __float_as_uint(v), 0x121, 0xF)));
    v = fmaxf(v, __uint_as_float(DPPU(0xFF800000u, __float_as_uint(v), 0x122, 0xF)));
    v = fmaxf(v, __uint_as_float(DPPU(0xFF800000u, __float_as_uint(v), 0x124, 0xF)));
    v = fmaxf(v, __uint_as_float(DPPU(0xFF800000u, __float_as_uint(v), 0x128, 0xF)));
    return v;
}
__device__ __forceinline__ float row_allsum_f(float v) {
    v += __uint_as_float(DPPU(0u, __float_as_uint(v), 0x121, 0xF));
    v += __uint_as_float(DPPU(0u, __float_as_uint(v), 0x122, 0xF));
    v += __uint_as_float(DPPU(0u, __float_as_uint(v), 0x124, 0xF));
    v += __uint_as_float(DPPU(0u, __float_as_uint(v), 0x128, 0xF));
    return v;
}
__device__ __forceinline__ float wave_sum_f(float v) {         // -> SGPR bcast
    v = row_allsum_f(v);
    v += __uint_as_float(DPPU(0u, __float_as_uint(v), 0x142, 0xA));
    v += __uint_as_float(DPPU(0u, __float_as_uint(v), 0x143, 0xC));
    return __uint_as_float((unsigned)__builtin_amdgcn_readlane((int)__float_as_uint(v), 63));
}

// ---------------------------------------------------------------------------
// Kernel 1: normalize. anchor rows (eps 1e-8) -> bf16 A; sample rows
// (eps 1e-12) -> bf16 s_norm. float4 input loads (2/lane).
// ---------------------------------------------------------------------------
__global__ __launch_bounds__(256) void norm_kernel(const float* __restrict__ anchor,
                                                   const float* __restrict__ sample,
                                                   unsigned short* __restrict__ Abf,
                                                   unsigned short* __restrict__ s_norm) {
    const int wave = threadIdx.x >> 6, lane = threadIdx.x & 63;
    const int row = blockIdx.x * 4 + wave;
    const bool is_anchor = row < N;
    const float* in = is_anchor ? anchor + (size_t)row * D
                                : sample + (size_t)(row - N) * D;
    const float eps = is_anchor ? 1e-8f : 1e-12f;

    const float4 v0 = *(const float4*)&in[lane * 4];
    const float4 v1 = *(const float4*)&in[256 + lane * 4];
    float ss = v0.x * v0.x + v0.y * v0.y + v0.z * v0.z + v0.w * v0.w
             + v1.x * v1.x + v1.y * v1.y + v1.z * v1.z + v1.w * v1.w;
#pragma unroll
    for (int off = 32; off > 0; off >>= 1) ss += __shfl_xor(ss, off);
    const float inv = 1.0f / fmaxf(sqrtf(ss), eps);

    unsigned short* out = is_anchor ? Abf + (size_t)row * D
                                    : s_norm + (size_t)(row - N) * D;
    ushort4 o0, o1;
    o0.x = f2bf(v0.x * inv); o0.y = f2bf(v0.y * inv);
    o0.z = f2bf(v0.z * inv); o0.w = f2bf(v0.w * inv);
    o1.x = f2bf(v1.x * inv); o1.y = f2bf(v1.y * inv);
    o1.z = f2bf(v1.z * inv); o1.w = f2bf(v1.w * inv);
    *(ushort4*)&out[lane * 4] = o0;
    *(ushort4*)&out[256 + lane * 4] = o1;
}

// ---------------------------------------------------------------------------
// Kernel 2: sim = A@A^T, bf16 MFMA, K = 512. 1024 balanced half-jobs
// (128 rows x 64 cols). Output = SORTABLE-MAPPED u16, staged through LDS
// (Tn normal + Tm mirror orientations, XOR-swizzled) so ALL global writes
// are 16B-wide fully-coalesced NONTEMPORAL stores (full 64B lines -> no
// partial-line RMW amplification; sim lands clean for the reader).
// ---------------------------------------------------------------------------
#define ATILE (128 * 64)
#define BTILE (64 * 64)

__device__ __forceinline__ void stage_ab(const unsigned short* __restrict__ A,
                                         unsigned short* As, unsigned short* Bs,
                                         int rowA, int colB, int kl, int t) {
#pragma unroll
    for (int i = 0; i < 4; ++i) {
        const int c = i * 256 + t;                 // 16B chunk id 0..1023
        const int r = c >> 3;                      // tile row 0..127
        const int ke = ((c & 7) ^ (r & 7)) * 8;    // swizzled k-element offset
        __builtin_amdgcn_global_load_lds(
            (const __attribute__((address_space(1))) void*)(A + (size_t)(rowA + r) * D + kl + ke),
            (__attribute__((address_space(3))) void*)(As + c * 8), 16, 0, 0);
    }
#pragma unroll
    for (int i = 0; i < 2; ++i) {
        const int c = i * 256 + t;                 // 0..511
        const int r = c >> 3;                      // B tile row 0..63
        const int ke = ((c & 7) ^ (r & 7)) * 8;
        __builtin_amdgcn_global_load_lds(
            (const __attribute__((address_space(1))) void*)(A + (size_t)(colB + r) * D + kl + ke),
            (__attribute__((address_space(3))) void*)(Bs + c * 8), 16, 0, 0);
    }
}

__global__ __launch_bounds__(256) void gemm_bf16(const unsigned short* __restrict__ Abf,
                                                 unsigned short* __restrict__ C) {
    // T1: XCD chunk swizzle (bijective, NJOB % 8 == 0).
    const int q = (blockIdx.x % 8) * (NJOB / 8) + blockIdx.x / 8;

    int bi, bj, h;
    if (q < 2 * NPAIR) {
        const int op = q >> 1;                 // strict pair index 0..495
        h = q & 1;
        bi = (int)(31.5f - sqrtf(31.5f * 31.5f - 2.f * (float)op));
        while (31 * bi - bi * (bi - 1) / 2 > op) --bi;
        while (31 * (bi + 1) - (bi + 1) * bi / 2 <= op) ++bi;
        bj = bi + 1 + (op - (31 * bi - bi * (bi - 1) / 2));
    } else {
        const int d = q - 2 * NPAIR;           // 0..31
        bi = bj = d >> 1;
        h = d & 1;
    }

    __shared__ __align__(16) unsigned short As[2 * ATILE];   // 2 x 16 KiB
    __shared__ __align__(16) unsigned short Bs[2 * BTILE];   // 2 x 8 KiB

    const int t = threadIdx.x;
    const int l = t & 63;
    const int w = t >> 6;
    const int wr = w >> 1, wc = w & 1;         // wave tile: 64 rows x 32 cols
    const int rowA = bi * 128;
    const int colB = bj * 128 + h * 64;
    const int lrow = l & 15, lgrp = l >> 4;

    f32x4 acc[4][2];
#pragma unroll
    for (int m = 0; m < 4; ++m)
#pragma unroll
        for (int n = 0; n < 2; ++n) acc[m][n] = (f32x4){0.f, 0.f, 0.f, 0.f};

    stage_ab(Abf, As, Bs, rowA, colB, 0, t);
    __syncthreads();

    for (int kc = 0; kc < 8; ++kc) {
        const int cur = kc & 1;
        if (kc < 7)
            stage_ab(Abf, As + (cur ^ 1) * ATILE, Bs + (cur ^ 1) * BTILE,
                     rowA, colB, (kc + 1) * 64, t);

        const char* AsB = (const char*)(As + cur * ATILE);
        const char* BsB = (const char*)(Bs + cur * BTILE);
#pragma unroll
        for (int kk = 0; kk < 2; ++kk) {
            s16x8 af[4], bfr[2];
#pragma unroll
            for (int m = 0; m < 4; ++m) {
                const int row = wr * 64 + m * 16 + lrow;
                af[m] = *(const s16x8*)(AsB + row * 128 + (((kk * 4 + lgrp) ^ (row & 7)) * 16));
            }
#pragma unroll
            for (int n = 0; n < 2; ++n) {
                const int row = wc * 32 + n * 16 + lrow;   // B tile row 0..63
                bfr[n] = *(const s16x8*)(BsB + row * 128 + (((kk * 4 + lgrp) ^ (row & 7)) * 16));
            }
#pragma unroll
            for (int m = 0; m < 4; ++m)
#pragma unroll
                for (int n = 0; n < 2; ++n)
                    acc[m][n] = __builtin_amdgcn_mfma_f32_16x16x32_bf16(af[m], bfr[n], acc[m][n], 0, 0, 0);
        }
        __syncthreads();   // final iter's barrier also frees As/Bs for reuse
    }

    // ---- epilogue: stage both orientations in LDS, then wide NT stores ----
    unsigned short* Tn = As;             // [128][64] normal (16 KB of As)
    unsigned short* Tm = Bs;             // [64][128] mirror, XOR swizzled (16 KB)
#pragma unroll
    for (int m = 0; m < 4; ++m) {
#pragma unroll
        for (int n = 0; n < 2; ++n) {
            const int c = wc * 32 + n * 16 + lrow;        // 0..63
            const int r0 = wr * 64 + m * 16 + lgrp * 4;   // 0..124
#pragma unroll
            for (int j = 0; j < 4; ++j) {
                const unsigned short val = mapbf(acc[m][n][j]);
                Tn[(r0 + j) * 64 + c] = val;
                Tm[c * 128 + ((r0 + j) ^ ((c & 7) << 3))] = val;
            }
        }
    }
    __syncthreads();

    // normal block: 128 rows x 64 cols as 1024 16B chunks, coalesced NT.
#pragma unroll
    for (int i = 0; i < 4; ++i) {
        const int chunk = i * 256 + t;
        const int r = chunk >> 3;
        const int c8 = (chunk & 7) * 8;
        const u16x8 v = *(const u16x8*)&Tn[r * 64 + c8];
        __builtin_nontemporal_store(v, (u16x8*)&C[(size_t)(rowA + r) * N + colB + c8]);
    }
    if (bi != bj) {
        // mirror block: 64 rows x 128 cols as 1024 16B chunks, coalesced NT.
#pragma unroll
        for (int i = 0; i < 4; ++i) {
            const int chunk = i * 256 + t;
            const int c = chunk >> 4;          // 0..63
            const int r8 = (chunk & 15) * 8;   // 0..120
            const u16x8 v = *(const u16x8*)&Tm[c * 128 + (r8 ^ ((c & 7) << 3))];
            __builtin_nontemporal_store(v, (u16x8*)&C[(size_t)(colB + c) * N + rowA + r8]);
        }
    }
}

// ---------------------------------------------------------------------------
// Kernel 3: FUSED topk + loss. Threshold two-pass scan (ballot binary-search
// thresholds, DPP merges/softmax); sim rows read with NONTEMPORAL loads
// (read-once streaming data, keeps L2 clean for s_norm).
// ---------------------------------------------------------------------------
__device__ __forceinline__ void ins_top(unsigned* tk, unsigned c) {
#pragma unroll
    for (int q = 0; q < KPOS - 1; ++q) {
        const unsigned x = umax_(tk[q], c);
        c = umin_(tk[q], c);
        tk[q] = x;
    }
    tk[KPOS - 1] = umax_(tk[KPOS - 1], c);
}
__device__ __forceinline__ void ins_bot(unsigned* bk, unsigned c) {
#pragma unroll
    for (int q = 0; q < KNEG - 1; ++q) {
        const unsigned x = umin_(bk[q], c);
        c = umax_(bk[q], c);
        bk[q] = x;
    }
    bk[KNEG - 1] = umin_(bk[KNEG - 1], c);
}

__global__ __launch_bounds__(256) void fused_topk_loss(const unsigned short* __restrict__ sim,
                                                       const unsigned short* __restrict__ s_norm,
                                                       float* __restrict__ partials) {
    __shared__ float wsum[4];
    __shared__ unsigned cand_top[4][256];
    __shared__ unsigned cand_bot[4][256];
    __shared__ unsigned cnt[4][2];
    const int wave = threadIdx.x >> 6, lane = threadIdx.x & 63;
    const int ia = blockIdx.x * 4 + wave;
    const unsigned short* s = sim + (size_t)ia * N;
    const int cc = lane & 15;               // loss column selector
    const int g = lane >> 4;                // loss k-group

    if (lane == 0) { cnt[wave][0] = 0u; cnt[wave][1] = 0u; }

    // ---- preload the whole row: 8 independent NT 16B loads in flight ----
    const u32x4 d0 = __builtin_bit_cast(u32x4, __builtin_nontemporal_load((const u16x8*)&s[8 * lane]));
    const u32x4 d1 = __builtin_bit_cast(u32x4, __builtin_nontemporal_load((const u16x8*)&s[8 * (lane + 64)]));
    const u32x4 d2 = __builtin_bit_cast(u32x4, __builtin_nontemporal_load((const u16x8*)&s[8 * (lane + 128)]));
    const u32x4 d3 = __builtin_bit_cast(u32x4, __builtin_nontemporal_load((const u16x8*)&s[8 * (lane + 192)]));
    const u32x4 d4 = __builtin_bit_cast(u32x4, __builtin_nontemporal_load((const u16x8*)&s[8 * (lane + 256)]));
    const u32x4 d5 = __builtin_bit_cast(u32x4, __builtin_nontemporal_load((const u16x8*)&s[8 * (lane + 320)]));
    const u32x4 d6 = __builtin_bit_cast(u32x4, __builtin_nontemporal_load((const u16x8*)&s[8 * (lane + 384)]));
    const u32x4 d7 = __builtin_bit_cast(u32x4, __builtin_nontemporal_load((const u16x8*)&s[8 * (lane + 448)]));
    __builtin_amdgcn_sched_barrier(0);
    asm volatile("" ::: "memory");

    // ---- pass 1: lane max/min via packed trees ----
#define VMAX(v) pkmax(pkmax(v.x, v.y), pkmax(v.z, v.w))
#define VMIN(v) pkmin(pkmin(v.x, v.y), pkmin(v.z, v.w))
    unsigned mx = VMAX(d0), mn = VMIN(d0);
    mx = pkmax(mx, VMAX(d1)); mn = pkmin(mn, VMIN(d1));
    mx = pkmax(mx, VMAX(d2)); mn = pkmin(mn, VMIN(d2));
    mx = pkmax(mx, VMAX(d3)); mn = pkmin(mn, VMIN(d3));
    mx = pkmax(mx, VMAX(d4)); mn = pkmin(mn, VMIN(d4));
    mx = pkmax(mx, VMAX(d5)); mn = pkmin(mn, VMIN(d5));
    mx = pkmax(mx, VMAX(d6)); mn = pkmin(mn, VMIN(d6));
    mx = pkmax(mx, VMAX(d7)); mn = pkmin(mn, VMIN(d7));
#undef VMAX
#undef VMIN
    const unsigned lm = umax_(mx >> 16, mx & 0xFFFFu);
    const unsigned ln = umin_(mn >> 16, mn & 0xFFFFu);

    // ---- thresholds via ballot binary search (no DS-path ops) ----
    unsigned lo = 0u, hi = 0xFFFFu;
    while (lo < hi) {
        const unsigned mid = (lo + hi + 1u) >> 1;
        const int c = __popcll(__ballot(lm >= mid));
        if (c >= KPOS) lo = mid; else hi = mid - 1u;
    }
    const unsigned T5 = lo;
    lo = 0u; hi = 0xFFFFu;
    while (lo < hi) {
        const unsigned mid = (lo + hi) >> 1;
        const int c = __popcll(__ballot(ln <= mid));
        if (c >= KNEG) hi = mid; else lo = mid + 1u;
    }
    const unsigned T10 = lo;

    const unsigned t5g = (T5 == 0u) ? 0u : T5 - 1u;
    const unsigned t10g = (T10 >= 0xFFFFu) ? 0xFFFFu : T10 + 1u;
    const unsigned pair5 = t5g * 0x10001u;
    const unsigned pairA = t10g * 0x10001u;

    // ---- pass 2: sparse exact candidate collection ----
#define SCAN_DW(dd, base)                                                      \
    {                                                                          \
        const unsigned pt = pkmax(dd, pair5);                                  \
        const unsigned pb = pkmin(dd, pairA);                                  \
        if (pt != pair5 || pb != pairA) {                                      \
            const unsigned e0 = (dd) & 0xFFFFu, e1 = (dd) >> 16;               \
            if (e0 >= T5) { unsigned p = atomicAdd(&cnt[wave][0], 1u);         \
                cand_top[wave][p & 255u] = (e0 << 16) | (unsigned)((base) ^ 0xFFF); } \
            if (e1 >= T5) { unsigned p = atomicAdd(&cnt[wave][0], 1u);         \
                cand_top[wave][p & 255u] = (e1 << 16) | (unsigned)(((base) + 1) ^ 0xFFF); } \
            if (e0 <= T10) { unsigned p = atomicAdd(&cnt[wave][1], 1u);        \
                cand_bot[wave][p & 255u] = (e0 << 16) | (unsigned)(base); }    \
            if (e1 <= T10) { unsigned p = atomicAdd(&cnt[wave][1], 1u);        \
                cand_bot[wave][p & 255u] = (e1 << 16) | (unsigned)((base) + 1); } \
        }                                                                      \
    }
#define SCAN_VEC(dv, vb)                                                       \
    SCAN_DW(dv.x, (vb));      SCAN_DW(dv.y, (vb) + 2);                         \
    SCAN_DW(dv.z, (vb) + 4);  SCAN_DW(dv.w, (vb) + 6);
    SCAN_VEC(d0, 8 * lane)
    SCAN_VEC(d1, 8 * (lane + 64))
    SCAN_VEC(d2, 8 * (lane + 128))
    SCAN_VEC(d3, 8 * (lane + 192))
    SCAN_VEC(d4, 8 * (lane + 256))
    SCAN_VEC(d5, 8 * (lane + 320))
    SCAN_VEC(d6, 8 * (lane + 384))
    SCAN_VEC(d7, 8 * (lane + 448))
#undef SCAN_VEC
#undef SCAN_DW

    // ---- final exact selection from candidates (DPP wave merges) ----
    const unsigned ctT = umin_(cnt[wave][0], 256u);
    const unsigned ctB = umin_(cnt[wave][1], 256u);
    unsigned tk[KPOS], bk[KNEG];
#pragma unroll
    for (int q = 0; q < KPOS; ++q) tk[q] = 0u;
#pragma unroll
    for (int q = 0; q < KNEG; ++q) bk[q] = 0xFFFFFFFFu;
    for (unsigned c = lane; c < ctT; c += 64) ins_top(tk, cand_top[wave][c]);
    for (unsigned c = lane; c < ctB; c += 64) ins_bot(bk, cand_bot[wave][c]);

    int rowB = 0;                            // (cc==15 dummy stays 0)
#pragma unroll
    for (int it = 0; it < KPOS; ++it) {
        const unsigned m = wave_max_b(tk[0]);
        if (cc == it) rowB = (int)((m & 0xFFFu) ^ 0xFFFu);
        if (tk[0] == m) {
#pragma unroll
            for (int q = 0; q < KPOS - 1; ++q) tk[q] = tk[q + 1];
            tk[KPOS - 1] = 0u;
        }
    }
#pragma unroll
    for (int it = 0; it < KNEG; ++it) {
        const unsigned m = wave_min_b(bk[0]);
        if (cc == KPOS + it) rowB = (int)(m & 0xFFFu);
        if (bk[0] == m) {
#pragma unroll
            for (int q = 0; q < KNEG - 1; ++q) bk[q] = bk[q + 1];
            bk[KNEG - 1] = 0xFFFFFFFFu;
        }
    }

    // ---- loss: A rows = query rows (ia*5+p mod N), B cols = pos/neg ----
    const int rowA = (ia * KPOS + ((cc < KPOS) ? cc : 0)) & (N - 1);
    const unsigned short* pA = s_norm + (size_t)rowA * D + g * 8;
    const unsigned short* pB = s_norm + (size_t)rowB * D + g * 8;

    s16x8 a[16], b[16];
#pragma unroll
    for (int kk = 0; kk < 16; ++kk) {
        a[kk] = *(const s16x8*)(pA + kk * 32);
        b[kk] = *(const s16x8*)(pB + kk * 32);
    }
    __builtin_amdgcn_sched_barrier(0);      // pin: all 32 loads issued first
    asm volatile("" ::: "memory");

    f32x4 acc = (f32x4){0.f, 0.f, 0.f, 0.f};
#pragma unroll
    for (int kk = 0; kk < 16; ++kk)
        acc = __builtin_amdgcn_mfma_f32_16x16x32_bf16(a[kk], b[kk], acc, 0, 0, 0);

    float lsum = 0.f;
#pragma unroll
    for (int j = 0; j < 4; ++j) {
        const int p = g * 4 + j;                 // output row (query p)
        const float logit = acc[j] * 10.f;
        const bool isneg = (cc >= KPOS) && (cc < 15);
        const bool ispos = (cc == p);
        const float x = (ispos || isneg) ? logit : -__builtin_inff();
        const float m = row_allmax_f(x);                     // DPP 16-lane
        const float e = (ispos || isneg) ? expf(logit - m) : 0.f;
        const float sx = row_allsum_f(e);                    // DPP 16-lane
        const float l0 = row_allsum_f(ispos ? logit : 0.f);  // DPP 16-lane
        if (p < KPOS && ispos) lsum += logf(sx) + m - l0;    // one lane per row
    }

    const float ltot = wave_sum_f(lsum);
    if (lane == 0) wsum[wave] = ltot;
    __syncthreads();
    if (threadIdx.x == 0)
        partials[blockIdx.x] = wsum[0] + wsum[1] + wsum[2] + wsum[3];
}

// ---------------------------------------------------------------------------
// Kernel 4: final deterministic reduce of 1024 block partials.
// ---------------------------------------------------------------------------
__global__ __launch_bounds__(256) void reduce_kernel(const float* __restrict__ partials,
                                                     float* __restrict__ out) {
    __shared__ float wsum[4];
    const int wave = threadIdx.x >> 6, lane = threadIdx.x & 63;
    float s = partials[threadIdx.x] + partials[threadIdx.x + 256] +
              partials[threadIdx.x + 512] + partials[threadIdx.x + 768];
#pragma unroll
    for (int off = 32; off > 0; off >>= 1) s += __shfl_xor(s, off);
    if (lane == 0) wsum[wave] = s;
    __syncthreads();
    if (threadIdx.x == 0)
        *out = (wsum[0] + wsum[1] + wsum[2] + wsum[3]) * (1.0f / (float)(N * KPOS));
}

// ---------------------------------------------------------------------------
extern "C" void kernel_launch(void* const* d_in, const int* in_sizes, int n_in,
                              void* d_out, int out_size, void* d_ws, size_t ws_size,
                              hipStream_t stream) {
    const float* anchor = (const float*)d_in[0];
    const float* sample = (const float*)d_in[1];
    float* out = (float*)d_out;

    char* ws = (char*)d_ws;
    unsigned short* Abf    = (unsigned short*)ws;                               // 4 MiB
    unsigned short* s_norm = (unsigned short*)(ws + (size_t)4 * 1024 * 1024);   // 4 MiB
    unsigned short* sim    = (unsigned short*)(ws + (size_t)8 * 1024 * 1024);   // 32 MiB
    float* partials = (float*)(ws + (size_t)40 * 1024 * 1024);                  // 4 KiB

    norm_kernel<<<2048, 256, 0, stream>>>(anchor, sample, Abf, s_norm);

    gemm_bf16<<<NJOB, 256, 0, stream>>>(Abf, sim);

    fused_topk_loss<<<N / 4, 256, 0, stream>>>(sim, s_norm, partials);

    reduce_kernel<<<1, 256, 0, stream>>>(partials, out);
}